// Round 1
// baseline (844.733 us; speedup 1.0000x reference)
//
#include <hip/hip_runtime.h>

#define N_NODESC 50000
#define N_EDGESC 800000
#define N_GRAPHSC 512
#define DF 128
#define BN_EPSF 1e-5f

static __device__ __forceinline__ float4 f4zero() { return make_float4(0.f, 0.f, 0.f, 0.f); }

// ---------------- CSR build ----------------
__global__ __launch_bounds__(256) void k_count(const int* __restrict__ dst, int* __restrict__ counts) {
    int e = blockIdx.x * 256 + threadIdx.x;
    if (e < N_EDGESC) atomicAdd(&counts[dst[e]], 1);
}

// single-block exclusive scan over 50000 counts (in-place -> offsets), also inits cursor
__global__ __launch_bounds__(1024) void k_scan(int* __restrict__ cnt_off, int* __restrict__ cursor) {
    __shared__ int part[1024];
    int t = threadIdx.x;
    const int CH = 49;  // 1024*49 = 50176 >= 50000
    int lo = t * CH, hi = lo + CH;
    if (lo > N_NODESC) lo = N_NODESC;
    if (hi > N_NODESC) hi = N_NODESC;
    int s = 0;
    for (int i = lo; i < hi; i++) s += cnt_off[i];
    part[t] = s;
    __syncthreads();
    for (int ofs = 1; ofs < 1024; ofs <<= 1) {
        int v = (t >= ofs) ? part[t - ofs] : 0;
        __syncthreads();
        part[t] += v;
        __syncthreads();
    }
    int run = (t == 0) ? 0 : part[t - 1];
    for (int i = lo; i < hi; i++) {
        int c = cnt_off[i];
        cnt_off[i] = run;
        cursor[i] = run;
        run += c;
    }
    if (t == 1023) cnt_off[N_NODESC] = run;  // = N_EDGESC
}

__global__ __launch_bounds__(256) void k_scatter(const int* __restrict__ src, const int* __restrict__ dst,
                                                 int* __restrict__ cursor, int* __restrict__ csr) {
    int e = blockIdx.x * 256 + threadIdx.x;
    if (e < N_EDGESC) {
        int d = dst[e];
        int pos = atomicAdd(&cursor[d], 1);
        csr[pos] = src[e];
    }
}

// ---------------- gather aggregation: zin = (1+eps)*h + sum_{incoming} h[src] ----------------
// 32 lanes (float4) per node, 8 nodes per 256-thread block
__global__ __launch_bounds__(256) void k_gather(const float* __restrict__ h, const int* __restrict__ off,
                                                const int* __restrict__ csr, const float* __restrict__ epsArr,
                                                int layer, float* __restrict__ zin) {
    int grp = threadIdx.x >> 5;
    int lane = threadIdx.x & 31;
    int n = blockIdx.x * 8 + grp;
    if (n >= N_NODESC) return;
    const float4* h4 = (const float4*)h;
    float e1 = 1.0f + epsArr[layer];
    float4 v = h4[n * 32 + lane];
    float4 acc = make_float4(e1 * v.x, e1 * v.y, e1 * v.z, e1 * v.w);
    int s = off[n], t = off[n + 1];
    for (int k = s; k < t; k++) {
        int m = csr[k];
        float4 u = h4[m * 32 + lane];
        acc.x += u.x; acc.y += u.y; acc.z += u.z; acc.w += u.w;
    }
    ((float4*)zin)[n * 32 + lane] = acc;
}

// ---------------- fp32 tiled GEMM: C[MxN] = A[Mx128] @ W[128xN] + bias, tile 64x64 ----------------
template <bool RELU>
__global__ __launch_bounds__(256) void k_gemm(const float* __restrict__ A, const float* __restrict__ W,
                                              const float* __restrict__ bias, float* __restrict__ C) {
    __shared__ float As[64 * DF];   // 32 KB, row-major [row][k]
    __shared__ float Ws[DF * 64];   // 32 KB, [k][col]
    int tid = threadIdx.x;
    int m0 = blockIdx.x * 64;
    int c0 = blockIdx.y * 64;

    // stage A tile (coalesced float4)
#pragma unroll
    for (int i = 0; i < 8; i++) {
        int f4 = i * 256 + tid;          // 2048 float4
        int r = f4 >> 5;                 // 32 float4 per row
        int k4 = (f4 & 31) << 2;
        float4 v = (m0 + r < N_NODESC) ? *(const float4*)&A[(size_t)(m0 + r) * DF + k4] : f4zero();
        *(float4*)&As[r * DF + k4] = v;
    }
    // stage W tile
#pragma unroll
    for (int i = 0; i < 8; i++) {
        int f4 = i * 256 + tid;          // 2048 float4
        int k = f4 >> 4;                 // 16 float4 per row of 64
        int c4 = (f4 & 15) << 2;
        float4 v = *(const float4*)&W[k * DF + c0 + c4];
        *(float4*)&Ws[k * 64 + c4] = v;
    }
    __syncthreads();

    int tx = tid & 15, ty = tid >> 4;
    int rr = ty * 4, cc = tx * 4;
    float acc[4][4];
#pragma unroll
    for (int r = 0; r < 4; r++)
#pragma unroll
        for (int c = 0; c < 4; c++) acc[r][c] = 0.f;

    for (int k = 0; k < DF; k += 4) {
        float4 w0 = *(const float4*)&Ws[(k + 0) * 64 + cc];
        float4 w1 = *(const float4*)&Ws[(k + 1) * 64 + cc];
        float4 w2 = *(const float4*)&Ws[(k + 2) * 64 + cc];
        float4 w3 = *(const float4*)&Ws[(k + 3) * 64 + cc];
#pragma unroll
        for (int r = 0; r < 4; r++) {
            float4 a = *(const float4*)&As[(rr + r) * DF + k];
            acc[r][0] = fmaf(a.x, w0.x, acc[r][0]);
            acc[r][1] = fmaf(a.x, w0.y, acc[r][1]);
            acc[r][2] = fmaf(a.x, w0.z, acc[r][2]);
            acc[r][3] = fmaf(a.x, w0.w, acc[r][3]);
            acc[r][0] = fmaf(a.y, w1.x, acc[r][0]);
            acc[r][1] = fmaf(a.y, w1.y, acc[r][1]);
            acc[r][2] = fmaf(a.y, w1.z, acc[r][2]);
            acc[r][3] = fmaf(a.y, w1.w, acc[r][3]);
            acc[r][0] = fmaf(a.z, w2.x, acc[r][0]);
            acc[r][1] = fmaf(a.z, w2.y, acc[r][1]);
            acc[r][2] = fmaf(a.z, w2.z, acc[r][2]);
            acc[r][3] = fmaf(a.z, w2.w, acc[r][3]);
            acc[r][0] = fmaf(a.w, w3.x, acc[r][0]);
            acc[r][1] = fmaf(a.w, w3.y, acc[r][1]);
            acc[r][2] = fmaf(a.w, w3.z, acc[r][2]);
            acc[r][3] = fmaf(a.w, w3.w, acc[r][3]);
        }
    }

    float4 b = *(const float4*)&bias[c0 + cc];
#pragma unroll
    for (int r = 0; r < 4; r++) {
        int row = m0 + rr + r;
        if (row < N_NODESC) {
            float4 o;
            o.x = acc[r][0] + b.x;
            o.y = acc[r][1] + b.y;
            o.z = acc[r][2] + b.z;
            o.w = acc[r][3] + b.w;
            if (RELU) {
                o.x = fmaxf(o.x, 0.f); o.y = fmaxf(o.y, 0.f);
                o.z = fmaxf(o.z, 0.f); o.w = fmaxf(o.w, 0.f);
            }
            *(float4*)&C[(size_t)row * DF + c0 + cc] = o;
        }
    }
}

// ---------------- BN column stats (sum, sumsq) ----------------
__global__ __launch_bounds__(256) void k_stats(const float* __restrict__ Z, float* __restrict__ st) {
    int c = threadIdx.x & (DF - 1);
    int ro = threadIdx.x >> 7;  // 0 or 1
    const int CH = 196;         // 256 blocks * 196 >= 50000
    int r0 = blockIdx.x * CH + ro;
    int r1 = blockIdx.x * CH + CH;
    if (r1 > N_NODESC) r1 = N_NODESC;
    float s = 0.f, s2 = 0.f;
    for (int r = r0; r < r1; r += 2) {
        float v = Z[(size_t)r * DF + c];
        s += v;
        s2 += v * v;
    }
    atomicAdd(&st[c], s);
    atomicAdd(&st[DF + c], s2);
}

// ---------------- BN apply (+optional ReLU) ----------------
template <bool RELU>
__global__ __launch_bounds__(256) void k_bn(const float* __restrict__ Z, const float* __restrict__ st,
                                            const float* __restrict__ gamma, const float* __restrict__ beta,
                                            float* __restrict__ H) {
    int i4 = blockIdx.x * 256 + threadIdx.x;
    if (i4 >= N_NODESC * DF / 4) return;
    int c = (i4 & (DF / 4 - 1)) << 2;
    const float invN = 1.0f / (float)N_NODESC;
    float4 z = ((const float4*)Z)[i4];
    float zz[4] = {z.x, z.y, z.z, z.w};
    float o[4];
#pragma unroll
    for (int j = 0; j < 4; j++) {
        float mean = st[c + j] * invN;
        float var = st[DF + c + j] * invN - mean * mean;
        float sc = gamma[c + j] * rsqrtf(var + BN_EPSF);
        float v = (zz[j] - mean) * sc + beta[c + j];
        if (RELU) v = fmaxf(v, 0.f);
        o[j] = v;
    }
    ((float4*)H)[i4] = make_float4(o[0], o[1], o[2], o[3]);
}

// ---------------- global mean pool over sorted batch ids ----------------
static __device__ int lbound(const int* __restrict__ a, int n, int key) {
    int lo = 0, hi = n;
    while (lo < hi) {
        int mid = (lo + hi) >> 1;
        if (a[mid] < key) lo = mid + 1; else hi = mid;
    }
    return lo;
}

__global__ __launch_bounds__(128) void k_pool(const float* __restrict__ H, const int* __restrict__ batch,
                                              float* __restrict__ out) {
    __shared__ int bnds[2];
    int g = blockIdx.x;
    if (threadIdx.x == 0) {
        bnds[0] = lbound(batch, N_NODESC, g);
        bnds[1] = lbound(batch, N_NODESC, g + 1);
    }
    __syncthreads();
    int lo = bnds[0], hi = bnds[1];
    float s = 0.f;
    for (int r = lo; r < hi; r++) s += H[(size_t)r * DF + threadIdx.x];
    int cnt = hi - lo;
    out[g * DF + threadIdx.x] = s / (float)(cnt > 0 ? cnt : 1);
}

extern "C" void kernel_launch(void* const* d_in, const int* in_sizes, int n_in,
                              void* d_out, int out_size, void* d_ws, size_t ws_size,
                              hipStream_t stream) {
    const float* x     = (const float*)d_in[0];
    const int*   ei    = (const int*)d_in[1];   // (2, E): row0=src, row1=dst
    const int*   batch = (const int*)d_in[2];
    const float* W1    = (const float*)d_in[3];
    const float* b1    = (const float*)d_in[4];
    const float* W2    = (const float*)d_in[5];
    const float* b2    = (const float*)d_in[6];
    const float* eps   = (const float*)d_in[7];
    const float* gamma = (const float*)d_in[8];
    const float* beta  = (const float*)d_in[9];
    float* out = (float*)d_out;

    // workspace carve-up (~80.4 MB total)
    char* ws = (char*)d_ws;
    size_t o = 0;
    auto alloc = [&](size_t bytes) -> char* {
        char* p = ws + o;
        o += (bytes + 255) & ~(size_t)255;
        return p;
    };
    int* off    = (int*)alloc((N_NODESC + 1) * sizeof(int));
    int* cursor = (int*)alloc(N_NODESC * sizeof(int));
    int* csr    = (int*)alloc(N_EDGESC * sizeof(int));
    float* st   = (float*)alloc(2 * DF * sizeof(float));
    float* bufA = (float*)alloc((size_t)N_NODESC * DF * sizeof(float));
    float* bufB = (float*)alloc((size_t)N_NODESC * DF * sizeof(float));
    float* bufC = (float*)alloc((size_t)N_NODESC * DF * sizeof(float));
    (void)ws_size; (void)in_sizes; (void)n_in; (void)out_size;

    const int* srcA = ei;
    const int* dstA = ei + N_EDGESC;

    // CSR build (once, reused by all 3 layers)
    hipMemsetAsync(off, 0, (N_NODESC + 1) * sizeof(int), stream);
    k_count<<<(N_EDGESC + 255) / 256, 256, 0, stream>>>(dstA, off);
    k_scan<<<1, 1024, 0, stream>>>(off, cursor);
    k_scatter<<<(N_EDGESC + 255) / 256, 256, 0, stream>>>(srcA, dstA, cursor, csr);

    dim3 gemm_grid((N_NODESC + 63) / 64, DF / 64);
    int bn_grid = (N_NODESC * DF / 4 + 255) / 256;

    for (int l = 0; l < 3; l++) {
        const float* hin = (l == 0) ? x : bufC;
        k_gather<<<(N_NODESC + 7) / 8, 256, 0, stream>>>(hin, off, csr, eps, l, bufA);
        k_gemm<true><<<gemm_grid, 256, 0, stream>>>(bufA, W1 + (size_t)l * DF * DF, b1 + l * DF, bufB);
        k_gemm<false><<<gemm_grid, 256, 0, stream>>>(bufB, W2 + (size_t)l * DF * DF, b2 + l * DF, bufA);
        hipMemsetAsync(st, 0, 2 * DF * sizeof(float), stream);
        k_stats<<<256, 256, 0, stream>>>(bufA, st);
        if (l < 2)
            k_bn<true><<<bn_grid, 256, 0, stream>>>(bufA, st, gamma + l * DF, beta + l * DF, bufC);
        else
            k_bn<false><<<bn_grid, 256, 0, stream>>>(bufA, st, gamma + l * DF, beta + l * DF, bufC);
    }
    k_pool<<<N_GRAPHSC, DF, 0, stream>>>(bufC, batch, out);
}

// Round 2
// 542.244 us; speedup vs baseline: 1.5578x; 1.5578x over previous
//
#include <hip/hip_runtime.h>

#define N_NODESC 50000
#define N_EDGESC 800000
#define N_GRAPHSC 512
#define DF 128
#define BN_EPSF 1e-5f

typedef _Float16 half8 __attribute__((ext_vector_type(8)));
typedef _Float16 half4v __attribute__((ext_vector_type(4)));
typedef float floatx4 __attribute__((ext_vector_type(4)));

// ---------------- CSR build ----------------
__global__ __launch_bounds__(256) void k_count(const int* __restrict__ dst, int* __restrict__ counts) {
    int e = blockIdx.x * 256 + threadIdx.x;
    if (e < N_EDGESC) atomicAdd(&counts[dst[e]], 1);
}

// multi-block scan, step 1: block-local exclusive scan of counts -> off, block totals -> partials
__global__ __launch_bounds__(1024) void k_scan1(int* __restrict__ off, int* __restrict__ partials) {
    __shared__ int sh[1024];
    int t = threadIdx.x;
    int i = blockIdx.x * 1024 + t;
    int v = (i < N_NODESC) ? off[i] : 0;
    sh[t] = v;
    __syncthreads();
    for (int ofs = 1; ofs < 1024; ofs <<= 1) {
        int u = (t >= ofs) ? sh[t - ofs] : 0;
        __syncthreads();
        sh[t] += u;
        __syncthreads();
    }
    if (i < N_NODESC) off[i] = sh[t] - v;  // local exclusive
    if (t == 1023) partials[blockIdx.x] = sh[1023];
}

// step 2: inclusive scan of 49 partials (one small block)
__global__ __launch_bounds__(64) void k_scan2(int* __restrict__ partials, int nparts) {
    __shared__ int sh[64];
    int t = threadIdx.x;
    sh[t] = (t < nparts) ? partials[t] : 0;
    __syncthreads();
    for (int ofs = 1; ofs < 64; ofs <<= 1) {
        int u = (t >= ofs) ? sh[t - ofs] : 0;
        __syncthreads();
        sh[t] += u;
        __syncthreads();
    }
    if (t < nparts) partials[t] = sh[t];
}

// step 3: add block base, emit cursor, set off[N]
__global__ __launch_bounds__(1024) void k_scan3(int* __restrict__ off, const int* __restrict__ partials,
                                                int* __restrict__ cursor) {
    int t = threadIdx.x;
    int i = blockIdx.x * 1024 + t;
    if (i < N_NODESC) {
        int base = blockIdx.x ? partials[blockIdx.x - 1] : 0;
        int o = off[i] + base;
        off[i] = o;
        cursor[i] = o;
    }
    if (i == 0) off[N_NODESC] = N_EDGESC;
}

__global__ __launch_bounds__(256) void k_scatter(const int* __restrict__ src, const int* __restrict__ dst,
                                                 int* __restrict__ cursor, int* __restrict__ csr) {
    int e = blockIdx.x * 256 + threadIdx.x;
    if (e < N_EDGESC) {
        int d = dst[e];
        int pos = atomicAdd(&cursor[d], 1);
        csr[pos] = src[e];
    }
}

// ---------------- x fp32 -> fp16 ----------------
__global__ __launch_bounds__(256) void k_convX(const float* __restrict__ x, _Float16* __restrict__ h) {
    int i4 = blockIdx.x * 256 + threadIdx.x;
    if (i4 >= N_NODESC * DF / 4) return;
    float4 v = ((const float4*)x)[i4];
    half4v o;
    o[0] = (_Float16)v.x; o[1] = (_Float16)v.y; o[2] = (_Float16)v.z; o[3] = (_Float16)v.w;
    ((half4v*)h)[i4] = o;
}

// ---------------- weight repack: fp32 [k][n] -> fp16 B-fragment order ----------------
// For matrix m (0..2 = W1 layer m, 3..5 = W2 layer m-3), chunk p in [0,2048):
//   ntile=p>>8, kstep=(p>>6)&3, lane=p&63 ; n=ntile*16+(lane&15), kb=kstep*32+(lane>>4)*8
//   out[m][p][j] = (fp16) W[kb+j][n]
__global__ __launch_bounds__(256) void k_convW(const float* __restrict__ W1, const float* __restrict__ W2,
                                               half8* __restrict__ wf) {
    int t = blockIdx.x * 256 + threadIdx.x;
    if (t >= 6 * 2048) return;
    int m = t >> 11;
    int p = t & 2047;
    int ntile = p >> 8;
    int ks = (p >> 6) & 3;
    int l = p & 63;
    int n = ntile * 16 + (l & 15);
    int kb = ks * 32 + (l >> 4) * 8;
    const float* W = (m < 3) ? (W1 + (size_t)m * DF * DF) : (W2 + (size_t)(m - 3) * DF * DF);
    half8 o;
#pragma unroll
    for (int j = 0; j < 8; j++) o[j] = (_Float16)W[(size_t)(kb + j) * DF + n];
    wf[t] = o;
}

// ---------------- gather aggregation (fp16 in, fp16 out, fp32 accum) ----------------
// 16 lanes per node, lane j handles halfs [8j, 8j+8)
__global__ __launch_bounds__(256) void k_gather(const _Float16* __restrict__ H, const int* __restrict__ off,
                                                const int* __restrict__ csr, const float* __restrict__ epsArr,
                                                int layer, _Float16* __restrict__ A) {
    int n = blockIdx.x * 16 + (threadIdx.x >> 4);
    int j = threadIdx.x & 15;
    if (n >= N_NODESC) return;
    const half8* Hr = (const half8*)H;
    float e1 = 1.0f + epsArr[layer];
    half8 v = Hr[n * 16 + j];
    float acc[8];
#pragma unroll
    for (int i = 0; i < 8; i++) acc[i] = e1 * (float)v[i];
    int s = off[n], t = off[n + 1];
    for (int k = s; k < t; k++) {
        int m = csr[k];
        half8 u = Hr[m * 16 + j];
#pragma unroll
        for (int i = 0; i < 8; i++) acc[i] += (float)u[i];
    }
    half8 o;
#pragma unroll
    for (int i = 0; i < 8; i++) o[i] = (_Float16)acc[i];
    ((half8*)A)[n * 16 + j] = o;
}

// ---------------- f16 MFMA GEMM: C[50000x128] = A @ W(+bias), tile 64 rows x 128 cols ----------------
// Wfrag: 2048 half8 chunks in exact B-fragment order (see k_convW).
// wave handles 16 rows; 8 n-tiles x 4 k-steps of 16x16x32 MFMA.
template <bool RELU, bool OUT32>
__global__ __launch_bounds__(256) void k_gemm(const _Float16* __restrict__ A, const half8* __restrict__ Wfrag,
                                              const float* __restrict__ bias, void* __restrict__ Cout) {
    __shared__ half8 Wlds[2048];  // 32 KB
    int tid = threadIdx.x;
    {
        const float4* wsrc = (const float4*)Wfrag;
        float4* wdst = (float4*)Wlds;
#pragma unroll
        for (int i = 0; i < 8; i++) wdst[i * 256 + tid] = wsrc[i * 256 + tid];
    }
    __syncthreads();

    int wave = tid >> 6, lane = tid & 63;
    int q = lane >> 4, c = lane & 15;
    int row = blockIdx.x * 64 + wave * 16 + c;
    bool rowok = row < N_NODESC;

    // prefetch all 4 A-fragments (one per k-step)
    half8 af[4];
    half8 zf = {};
#pragma unroll
    for (int ks = 0; ks < 4; ks++) {
        af[ks] = rowok ? *(const half8*)(A + (size_t)row * DF + ks * 32 + q * 8) : zf;
    }

    floatx4 acc[8];
#pragma unroll
    for (int nt = 0; nt < 8; nt++) acc[nt] = (floatx4)(0.0f);

#pragma unroll
    for (int ks = 0; ks < 4; ks++) {
#pragma unroll
        for (int nt = 0; nt < 8; nt++) {
            half8 wfr = Wlds[(nt * 4 + ks) * 64 + lane];
            acc[nt] = __builtin_amdgcn_mfma_f32_16x16x32_f16(af[ks], wfr, acc[nt], 0, 0, 0);
        }
    }

    // D: row = blockbase + wave*16 + q*4 + r, col = nt*16 + c
    int orow0 = blockIdx.x * 64 + wave * 16 + q * 4;
#pragma unroll
    for (int nt = 0; nt < 8; nt++) {
        float b = bias[nt * 16 + c];
#pragma unroll
        for (int r = 0; r < 4; r++) {
            int orow = orow0 + r;
            if (orow < N_NODESC) {
                float v = acc[nt][r] + b;
                if (RELU) v = fmaxf(v, 0.0f);
                if (OUT32)
                    ((float*)Cout)[(size_t)orow * DF + nt * 16 + c] = v;
                else
                    ((_Float16*)Cout)[(size_t)orow * DF + nt * 16 + c] = (_Float16)v;
            }
        }
    }
}

// ---------------- BN column stats (sum, sumsq) from fp32 z ----------------
__global__ __launch_bounds__(256) void k_stats(const float* __restrict__ Z, float* __restrict__ st) {
    int c = threadIdx.x & (DF - 1);
    int ro = threadIdx.x >> 7;  // 0 or 1
    const int CH = 196;         // 256 blocks * 196 >= 50000
    int r0 = blockIdx.x * CH + ro;
    int r1 = blockIdx.x * CH + CH;
    if (r1 > N_NODESC) r1 = N_NODESC;
    float s = 0.f, s2 = 0.f;
    for (int r = r0; r < r1; r += 2) {
        float v = Z[(size_t)r * DF + c];
        s += v;
        s2 += v * v;
    }
    atomicAdd(&st[c], s);
    atomicAdd(&st[DF + c], s2);
}

// ---------------- BN apply (+optional ReLU), fp32 z -> fp16 h ----------------
template <bool RELU>
__global__ __launch_bounds__(256) void k_bn(const float* __restrict__ Z, const float* __restrict__ st,
                                            const float* __restrict__ gamma, const float* __restrict__ beta,
                                            _Float16* __restrict__ H) {
    int i4 = blockIdx.x * 256 + threadIdx.x;
    if (i4 >= N_NODESC * DF / 4) return;
    int c = (i4 & (DF / 4 - 1)) << 2;
    const float invN = 1.0f / (float)N_NODESC;
    float4 z = ((const float4*)Z)[i4];
    float zz[4] = {z.x, z.y, z.z, z.w};
    half4v o;
#pragma unroll
    for (int j = 0; j < 4; j++) {
        float mean = st[c + j] * invN;
        float var = st[DF + c + j] * invN - mean * mean;
        float sc = gamma[c + j] * rsqrtf(var + BN_EPSF);
        float v = (zz[j] - mean) * sc + beta[c + j];
        if (RELU) v = fmaxf(v, 0.f);
        o[j] = (_Float16)v;
    }
    ((half4v*)H)[i4] = o;
}

// ---------------- global mean pool over sorted batch ids (fp16 h) ----------------
static __device__ int lbound(const int* __restrict__ a, int n, int key) {
    int lo = 0, hi = n;
    while (lo < hi) {
        int mid = (lo + hi) >> 1;
        if (a[mid] < key) lo = mid + 1; else hi = mid;
    }
    return lo;
}

__global__ __launch_bounds__(128) void k_pool(const _Float16* __restrict__ H, const int* __restrict__ batch,
                                              float* __restrict__ out) {
    __shared__ int bnds[2];
    int g = blockIdx.x;
    if (threadIdx.x == 0) {
        bnds[0] = lbound(batch, N_NODESC, g);
        bnds[1] = lbound(batch, N_NODESC, g + 1);
    }
    __syncthreads();
    int lo = bnds[0], hi = bnds[1];
    float s = 0.f;
    for (int r = lo; r < hi; r++) s += (float)H[(size_t)r * DF + threadIdx.x];
    int cnt = hi - lo;
    out[g * DF + threadIdx.x] = s / (float)(cnt > 0 ? cnt : 1);
}

extern "C" void kernel_launch(void* const* d_in, const int* in_sizes, int n_in,
                              void* d_out, int out_size, void* d_ws, size_t ws_size,
                              hipStream_t stream) {
    const float* x     = (const float*)d_in[0];
    const int*   ei    = (const int*)d_in[1];   // (2, E): row0=src, row1=dst
    const int*   batch = (const int*)d_in[2];
    const float* W1    = (const float*)d_in[3];
    const float* b1    = (const float*)d_in[4];
    const float* W2    = (const float*)d_in[5];
    const float* b2    = (const float*)d_in[6];
    const float* eps   = (const float*)d_in[7];
    const float* gamma = (const float*)d_in[8];
    const float* beta  = (const float*)d_in[9];
    float* out = (float*)d_out;

    char* ws = (char*)d_ws;
    size_t o = 0;
    auto alloc = [&](size_t bytes) -> char* {
        char* p = ws + o;
        o += (bytes + 255) & ~(size_t)255;
        return p;
    };
    int* off       = (int*)alloc((N_NODESC + 1) * sizeof(int));
    int* cursor    = (int*)alloc(N_NODESC * sizeof(int));
    int* csr       = (int*)alloc(N_EDGESC * sizeof(int));
    int* partials  = (int*)alloc(64 * sizeof(int));
    float* st      = (float*)alloc(2 * DF * sizeof(float));
    half8* wf      = (half8*)alloc((size_t)6 * 2048 * sizeof(half8));        // 192 KB
    _Float16* hbuf = (_Float16*)alloc((size_t)N_NODESC * DF * sizeof(_Float16));  // 12.8 MB
    _Float16* abuf = (_Float16*)alloc((size_t)N_NODESC * DF * sizeof(_Float16));
    _Float16* bbuf = (_Float16*)alloc((size_t)N_NODESC * DF * sizeof(_Float16));
    float* zbuf    = (float*)alloc((size_t)N_NODESC * DF * sizeof(float));        // 25.6 MB
    (void)ws_size; (void)in_sizes; (void)n_in; (void)out_size;

    const int* srcA = ei;
    const int* dstA = ei + N_EDGESC;

    const int NB_SCAN = (N_NODESC + 1023) / 1024;  // 49

    // CSR build
    hipMemsetAsync(off, 0, (N_NODESC + 1) * sizeof(int), stream);
    k_count<<<(N_EDGESC + 255) / 256, 256, 0, stream>>>(dstA, off);
    k_scan1<<<NB_SCAN, 1024, 0, stream>>>(off, partials);
    k_scan2<<<1, 64, 0, stream>>>(partials, NB_SCAN);
    k_scan3<<<NB_SCAN, 1024, 0, stream>>>(off, partials, cursor);
    k_scatter<<<(N_EDGESC + 255) / 256, 256, 0, stream>>>(srcA, dstA, cursor, csr);

    // weight repack + x conversion
    k_convW<<<(6 * 2048 + 255) / 256, 256, 0, stream>>>(W1, W2, wf);
    k_convX<<<(N_NODESC * DF / 4 + 255) / 256, 256, 0, stream>>>(x, hbuf);

    const int GEMM_GRID = (N_NODESC + 63) / 64;  // 782
    const int BN_GRID = (N_NODESC * DF / 4 + 255) / 256;

    for (int l = 0; l < 3; l++) {
        k_gather<<<(N_NODESC + 15) / 16, 256, 0, stream>>>(hbuf, off, csr, eps, l, abuf);
        k_gemm<true, false><<<GEMM_GRID, 256, 0, stream>>>(abuf, wf + (size_t)l * 2048,
                                                           b1 + l * DF, (void*)bbuf);
        k_gemm<false, true><<<GEMM_GRID, 256, 0, stream>>>(bbuf, wf + (size_t)(3 + l) * 2048,
                                                           b2 + l * DF, (void*)zbuf);
        hipMemsetAsync(st, 0, 2 * DF * sizeof(float), stream);
        k_stats<<<256, 256, 0, stream>>>(zbuf, st);
        if (l < 2)
            k_bn<true><<<BN_GRID, 256, 0, stream>>>(zbuf, st, gamma + l * DF, beta + l * DF, hbuf);
        else
            k_bn<false><<<BN_GRID, 256, 0, stream>>>(zbuf, st, gamma + l * DF, beta + l * DF, hbuf);
    }
    k_pool<<<N_GRAPHSC, DF, 0, stream>>>(hbuf, batch, out);
}

// Round 3
// 484.178 us; speedup vs baseline: 1.7447x; 1.1199x over previous
//
#include <hip/hip_runtime.h>

#define N_NODESC 50000
#define N_EDGESC 800000
#define N_GRAPHSC 512
#define DF 128
#define BN_EPSF 1e-5f

typedef _Float16 half8 __attribute__((ext_vector_type(8)));
typedef _Float16 half4v __attribute__((ext_vector_type(4)));
typedef _Float16 half2v __attribute__((ext_vector_type(2)));
typedef float floatx4 __attribute__((ext_vector_type(4)));

// ---------------- CSR build ----------------
__global__ __launch_bounds__(256) void k_count(const int* __restrict__ dst, int* __restrict__ counts) {
    int e = blockIdx.x * 256 + threadIdx.x;
    if (e < N_EDGESC) atomicAdd(&counts[dst[e]], 1);
}

__global__ __launch_bounds__(1024) void k_scan1(int* __restrict__ off, int* __restrict__ partials) {
    __shared__ int sh[1024];
    int t = threadIdx.x;
    int i = blockIdx.x * 1024 + t;
    int v = (i < N_NODESC) ? off[i] : 0;
    sh[t] = v;
    __syncthreads();
    for (int ofs = 1; ofs < 1024; ofs <<= 1) {
        int u = (t >= ofs) ? sh[t - ofs] : 0;
        __syncthreads();
        sh[t] += u;
        __syncthreads();
    }
    if (i < N_NODESC) off[i] = sh[t] - v;  // local exclusive
    if (t == 1023) partials[blockIdx.x] = sh[1023];
}

__global__ __launch_bounds__(64) void k_scan2(int* __restrict__ partials, int nparts) {
    __shared__ int sh[64];
    int t = threadIdx.x;
    sh[t] = (t < nparts) ? partials[t] : 0;
    __syncthreads();
    for (int ofs = 1; ofs < 64; ofs <<= 1) {
        int u = (t >= ofs) ? sh[t - ofs] : 0;
        __syncthreads();
        sh[t] += u;
        __syncthreads();
    }
    if (t < nparts) partials[t] = sh[t];
}

__global__ __launch_bounds__(1024) void k_scan3(int* __restrict__ off, const int* __restrict__ partials,
                                                int* __restrict__ cursor) {
    int t = threadIdx.x;
    int i = blockIdx.x * 1024 + t;
    if (i < N_NODESC) {
        int base = blockIdx.x ? partials[blockIdx.x - 1] : 0;
        int o = off[i] + base;
        off[i] = o;
        cursor[i] = o;
    }
    if (i == 0) off[N_NODESC] = N_EDGESC;
}

__global__ __launch_bounds__(256) void k_scatter(const int* __restrict__ src, const int* __restrict__ dst,
                                                 int* __restrict__ cursor, int* __restrict__ csr) {
    int e = blockIdx.x * 256 + threadIdx.x;
    if (e < N_EDGESC) {
        int d = dst[e];
        int pos = atomicAdd(&cursor[d], 1);
        csr[pos] = src[e];
    }
}

// ---------------- x fp32 -> fp16 ----------------
__global__ __launch_bounds__(256) void k_convX(const float* __restrict__ x, _Float16* __restrict__ h) {
    int i4 = blockIdx.x * 256 + threadIdx.x;
    if (i4 >= N_NODESC * DF / 4) return;
    float4 v = ((const float4*)x)[i4];
    half4v o;
    o[0] = (_Float16)v.x; o[1] = (_Float16)v.y; o[2] = (_Float16)v.z; o[3] = (_Float16)v.w;
    ((half4v*)h)[i4] = o;
}

// ---------------- weight repack: fp32 [k][n] -> fp16 B-fragment order ----------------
__global__ __launch_bounds__(256) void k_convW(const float* __restrict__ W1, const float* __restrict__ W2,
                                               half8* __restrict__ wf) {
    int t = blockIdx.x * 256 + threadIdx.x;
    if (t >= 6 * 2048) return;
    int m = t >> 11;
    int p = t & 2047;
    int ntile = p >> 8;
    int ks = (p >> 6) & 3;
    int l = p & 63;
    int n = ntile * 16 + (l & 15);
    int kb = ks * 32 + (l >> 4) * 8;
    const float* W = (m < 3) ? (W1 + (size_t)m * DF * DF) : (W2 + (size_t)(m - 3) * DF * DF);
    half8 o;
#pragma unroll
    for (int j = 0; j < 8; j++) o[j] = (_Float16)W[(size_t)(kb + j) * DF + n];
    wf[t] = o;
}

// ---------------- gather: wave-per-node, dword/lane, 4-edge unroll ----------------
// Also zeroes st (block 0) so gemm2's fused stats can atomicAdd into it.
__global__ __launch_bounds__(256) void k_gather(const _Float16* __restrict__ H, const int* __restrict__ off,
                                                const int* __restrict__ csr, const float* __restrict__ epsArr,
                                                int layer, _Float16* __restrict__ A, float* __restrict__ st) {
    if (blockIdx.x == 0 && threadIdx.x < 2 * DF) st[threadIdx.x] = 0.f;
    int n = blockIdx.x * 4 + (threadIdx.x >> 6);
    if (n >= N_NODESC) return;
    int lane = threadIdx.x & 63;
    const half2v* Hr = (const half2v*)H;
    size_t base = (size_t)n * 64 + lane;
    half2v v = Hr[base];
    float e1 = 1.0f + epsArr[layer];
    float a0 = e1 * (float)v[0];
    float a1 = e1 * (float)v[1];
    int s = off[n], t = off[n + 1];
    int k = s;
    for (; k + 4 <= t; k += 4) {
        int m0 = csr[k], m1 = csr[k + 1], m2 = csr[k + 2], m3 = csr[k + 3];
        half2v u0 = Hr[(size_t)m0 * 64 + lane];
        half2v u1 = Hr[(size_t)m1 * 64 + lane];
        half2v u2 = Hr[(size_t)m2 * 64 + lane];
        half2v u3 = Hr[(size_t)m3 * 64 + lane];
        a0 += (float)u0[0] + (float)u1[0] + (float)u2[0] + (float)u3[0];
        a1 += (float)u0[1] + (float)u1[1] + (float)u2[1] + (float)u3[1];
    }
    for (; k < t; k++) {
        half2v u = Hr[(size_t)csr[k] * 64 + lane];
        a0 += (float)u[0];
        a1 += (float)u[1];
    }
    half2v o;
    o[0] = (_Float16)a0;
    o[1] = (_Float16)a1;
    ((half2v*)A)[base] = o;
}

// ---------------- f16 MFMA GEMM, W fragments direct from global, optional fused stats ----------------
// Block: 64 rows x full N=128. Wave w: rows w*16..w*16+15; 8 n-tiles x 4 k-steps of 16x16x32.
template <bool RELU, bool FUSE_STATS>
__global__ __launch_bounds__(256) void k_gemm(const _Float16* __restrict__ A, const half8* __restrict__ Wfrag,
                                              const float* __restrict__ bias, _Float16* __restrict__ C,
                                              float* __restrict__ st) {
    int tid = threadIdx.x;
    int wave = tid >> 6, lane = tid & 63;
    int q = lane >> 4, c = lane & 15;
    int row = blockIdx.x * 64 + wave * 16 + c;
    bool rowok = row < N_NODESC;
    half8 zf = {};
    half8 af[4];
#pragma unroll
    for (int ks = 0; ks < 4; ks++)
        af[ks] = rowok ? *(const half8*)(A + (size_t)row * DF + ks * 32 + q * 8) : zf;

    floatx4 acc[8];
#pragma unroll
    for (int nt = 0; nt < 8; nt++) acc[nt] = (floatx4)(0.0f);

#pragma unroll
    for (int ks = 0; ks < 4; ks++) {
        half8 wfr[8];
#pragma unroll
        for (int nt = 0; nt < 8; nt++) wfr[nt] = Wfrag[(nt * 4 + ks) * 64 + lane];
#pragma unroll
        for (int nt = 0; nt < 8; nt++)
            acc[nt] = __builtin_amdgcn_mfma_f32_16x16x32_f16(af[ks], wfr[nt], acc[nt], 0, 0, 0);
    }

    // D layout: row = blockbase + wave*16 + q*4 + r, col = nt*16 + c
    int orow0 = blockIdx.x * 64 + wave * 16 + q * 4;
    float s1[8], s2[8];
#pragma unroll
    for (int nt = 0; nt < 8; nt++) {
        float b = bias[nt * 16 + c];
        float ls = 0.f, lq = 0.f;
#pragma unroll
        for (int r = 0; r < 4; r++) {
            int orow = orow0 + r;
            if (orow < N_NODESC) {
                float v = acc[nt][r] + b;
                if (RELU) v = fmaxf(v, 0.f);
                C[(size_t)orow * DF + nt * 16 + c] = (_Float16)v;
                ls += v;
                lq += v * v;
            }
        }
        s1[nt] = ls;
        s2[nt] = lq;
    }

    if constexpr (FUSE_STATS) {
        __shared__ float red[4][2][DF];
        // reduce over q-lanes (same column, different row-groups): lanes differing in bits 4..5
#pragma unroll
        for (int nt = 0; nt < 8; nt++) {
            s1[nt] += __shfl_xor(s1[nt], 16);
            s1[nt] += __shfl_xor(s1[nt], 32);
            s2[nt] += __shfl_xor(s2[nt], 16);
            s2[nt] += __shfl_xor(s2[nt], 32);
        }
        if (q == 0) {
#pragma unroll
            for (int nt = 0; nt < 8; nt++) {
                red[wave][0][nt * 16 + c] = s1[nt];
                red[wave][1][nt * 16 + c] = s2[nt];
            }
        }
        __syncthreads();
        int col = tid & 127, kind = (tid >> 7) & 1;
        float tot = red[0][kind][col] + red[1][kind][col] + red[2][kind][col] + red[3][kind][col];
        atomicAdd(&st[kind * DF + col], tot);
    }
}

// ---------------- BN apply (+optional ReLU), fp16 z -> fp16 h ----------------
template <bool RELU>
__global__ __launch_bounds__(256) void k_bn(const _Float16* __restrict__ Z, const float* __restrict__ st,
                                            const float* __restrict__ gamma, const float* __restrict__ beta,
                                            _Float16* __restrict__ H) {
    int i8 = blockIdx.x * 256 + threadIdx.x;
    if (i8 >= N_NODESC * DF / 8) return;
    int c0 = (i8 & 15) << 3;
    half8 z = ((const half8*)Z)[i8];
    half8 o;
    const float invN = 1.0f / (float)N_NODESC;
#pragma unroll
    for (int j = 0; j < 8; j++) {
        int cc = c0 + j;
        float mean = st[cc] * invN;
        float var = st[DF + cc] * invN - mean * mean;
        float sc = gamma[cc] * rsqrtf(var + BN_EPSF);
        float v = ((float)z[j] - mean) * sc + beta[cc];
        if (RELU) v = fmaxf(v, 0.f);
        o[j] = (_Float16)v;
    }
    ((half8*)H)[i8] = o;
}

// ---------------- global mean pool over sorted batch ids ----------------
static __device__ int lbound(const int* __restrict__ a, int n, int key) {
    int lo = 0, hi = n;
    while (lo < hi) {
        int mid = (lo + hi) >> 1;
        if (a[mid] < key) lo = mid + 1; else hi = mid;
    }
    return lo;
}

__global__ __launch_bounds__(128) void k_pool(const _Float16* __restrict__ H, const int* __restrict__ batch,
                                              float* __restrict__ out) {
    __shared__ int bnds[2];
    int g = blockIdx.x;
    if (threadIdx.x == 0) {
        bnds[0] = lbound(batch, N_NODESC, g);
        bnds[1] = lbound(batch, N_NODESC, g + 1);
    }
    __syncthreads();
    int lo = bnds[0], hi = bnds[1];
    float s = 0.f;
    for (int r = lo; r < hi; r++) s += (float)H[(size_t)r * DF + threadIdx.x];
    int cnt = hi - lo;
    out[g * DF + threadIdx.x] = s / (float)(cnt > 0 ? cnt : 1);
}

extern "C" void kernel_launch(void* const* d_in, const int* in_sizes, int n_in,
                              void* d_out, int out_size, void* d_ws, size_t ws_size,
                              hipStream_t stream) {
    const float* x     = (const float*)d_in[0];
    const int*   ei    = (const int*)d_in[1];   // (2, E): row0=src, row1=dst
    const int*   batch = (const int*)d_in[2];
    const float* W1    = (const float*)d_in[3];
    const float* b1    = (const float*)d_in[4];
    const float* W2    = (const float*)d_in[5];
    const float* b2    = (const float*)d_in[6];
    const float* eps   = (const float*)d_in[7];
    const float* gamma = (const float*)d_in[8];
    const float* beta  = (const float*)d_in[9];
    float* out = (float*)d_out;

    char* ws = (char*)d_ws;
    size_t o = 0;
    auto alloc = [&](size_t bytes) -> char* {
        char* p = ws + o;
        o += (bytes + 255) & ~(size_t)255;
        return p;
    };
    int* off       = (int*)alloc((N_NODESC + 1) * sizeof(int));
    int* cursor    = (int*)alloc(N_NODESC * sizeof(int));
    int* csr       = (int*)alloc(N_EDGESC * sizeof(int));
    int* partials  = (int*)alloc(64 * sizeof(int));
    float* st      = (float*)alloc(2 * DF * sizeof(float));
    half8* wf      = (half8*)alloc((size_t)6 * 2048 * sizeof(half8));
    _Float16* hbuf = (_Float16*)alloc((size_t)N_NODESC * DF * sizeof(_Float16));
    _Float16* abuf = (_Float16*)alloc((size_t)N_NODESC * DF * sizeof(_Float16));
    _Float16* bbuf = (_Float16*)alloc((size_t)N_NODESC * DF * sizeof(_Float16));
    _Float16* zbuf = (_Float16*)alloc((size_t)N_NODESC * DF * sizeof(_Float16));
    (void)ws_size; (void)in_sizes; (void)n_in; (void)out_size;

    const int* srcA = ei;
    const int* dstA = ei + N_EDGESC;

    const int NB_SCAN = (N_NODESC + 1023) / 1024;  // 49

    // CSR build
    hipMemsetAsync(off, 0, (N_NODESC + 1) * sizeof(int), stream);
    k_count<<<(N_EDGESC + 255) / 256, 256, 0, stream>>>(dstA, off);
    k_scan1<<<NB_SCAN, 1024, 0, stream>>>(off, partials);
    k_scan2<<<1, 64, 0, stream>>>(partials, NB_SCAN);
    k_scan3<<<NB_SCAN, 1024, 0, stream>>>(off, partials, cursor);
    k_scatter<<<(N_EDGESC + 255) / 256, 256, 0, stream>>>(srcA, dstA, cursor, csr);

    // weight repack + x conversion
    k_convW<<<(6 * 2048 + 255) / 256, 256, 0, stream>>>(W1, W2, wf);
    k_convX<<<(N_NODESC * DF / 4 + 255) / 256, 256, 0, stream>>>(x, hbuf);

    const int GATHER_GRID = (N_NODESC + 3) / 4;   // 12500
    const int GEMM_GRID = (N_NODESC + 63) / 64;   // 782
    const int BN_GRID = (N_NODESC * DF / 8 + 255) / 256;

    for (int l = 0; l < 3; l++) {
        k_gather<<<GATHER_GRID, 256, 0, stream>>>(hbuf, off, csr, eps, l, abuf, st);
        k_gemm<true, false><<<GEMM_GRID, 256, 0, stream>>>(abuf, wf + (size_t)l * 2048,
                                                           b1 + l * DF, bbuf, nullptr);
        k_gemm<false, true><<<GEMM_GRID, 256, 0, stream>>>(bbuf, wf + (size_t)(3 + l) * 2048,
                                                           b2 + l * DF, zbuf, st);
        if (l < 2)
            k_bn<true><<<BN_GRID, 256, 0, stream>>>(zbuf, st, gamma + l * DF, beta + l * DF, hbuf);
        else
            k_bn<false><<<BN_GRID, 256, 0, stream>>>(zbuf, st, gamma + l * DF, beta + l * DF, hbuf);
    }
    k_pool<<<N_GRAPHSC, DF, 0, stream>>>(hbuf, batch, out);
}